// Round 2
// baseline (277.472 us; speedup 1.0000x reference)
//
#include <hip/hip_runtime.h>

#define NN 16384      // N nodes
#define NE 65536      // E edges
#define H  32
#define BB 32         // batch
#define NPER 512
#define NL 4

#define BLK_DEG 256        // 64K threads : deg histogram
#define BLK_EMB 2048       // 512K threads: embedding gather
#define BLK_W   256        // 64K threads : 4 layers x 16 types x 1024 weights

// ---- fused prep: deg histogram + node-embed gather + per-type weight matrices (all layers) ----
__global__ void k_prep(const int* __restrict__ dst, const int* __restrict__ x_nodes,
                       const float* __restrict__ node_emb, const float* __restrict__ edge_emb,
                       const float* __restrict__ lin_w, const float* __restrict__ lin_b,
                       float* __restrict__ deg, float* __restrict__ x, float* __restrict__ Wt) {
    int b = blockIdx.x;
    if (b < BLK_DEG) {
        int e = b * 256 + threadIdx.x;
        atomicAdd(&deg[dst[e]], 1.0f);
    } else if (b < BLK_DEG + BLK_EMB) {
        int tid = (b - BLK_DEG) * 256 + threadIdx.x;   // n*32+h
        int n = tid >> 5, h = tid & 31;
        x[tid] = node_emb[x_nodes[n] * H + h];
    } else {
        int tid = (b - BLK_DEG - BLK_EMB) * 256 + threadIdx.x;  // l*16384 + t*1024 + io
        int l = tid >> 14;
        int rest = tid & 16383;
        int t = rest >> 10, io = rest & 1023;
        float acc = lin_b[l * 1024 + io];
#pragma unroll
        for (int j = 0; j < 8; ++j) {
            float e = edge_emb[(l * 16 + t) * 8 + j];
            e = e > 0.f ? e : 0.f;
            acc += e * lin_w[(l * 8 + j) * 1024 + io];
        }
        Wt[tid] = acc;
    }
}

// ---- exclusive prefix scan of deg (16384 values) in one block of 1024 threads ----
__global__ void k_scan(const float* __restrict__ deg, int* __restrict__ offs) {
    __shared__ int sums[1024];
    int t = threadIdx.x;
    int v[16];
    int s = 0;
#pragma unroll
    for (int i = 0; i < 16; ++i) { v[i] = (int)deg[t * 16 + i]; s += v[i]; }
    sums[t] = s;
    __syncthreads();
    for (int off = 1; off < 1024; off <<= 1) {
        int a = (t >= off) ? sums[t - off] : 0;
        __syncthreads();
        sums[t] += a;
        __syncthreads();
    }
    int run = (t > 0) ? sums[t - 1] : 0;
#pragma unroll
    for (int i = 0; i < 16; ++i) { offs[t * 16 + i] = run; run += v[i]; }
}

// ---- scatter edges into CSR slots: csr[slot] = src | (type<<14) ----
__global__ void k_scatter(const int* __restrict__ src, const int* __restrict__ dst,
                          const int* __restrict__ eattr, const int* __restrict__ offs,
                          int* __restrict__ cnt, int* __restrict__ csr) {
    int e = blockIdx.x * 256 + threadIdx.x;
    int d = dst[e];
    int slot = offs[d] + atomicAdd(&cnt[d], 1);
    csr[slot] = src[e] | (eattr[e] << 14);
}

// ---- fused per-layer: gather-aggregate + root matvec + bias (+relu) ----
// 32 lanes per node (2 nodes per wave64); lane o owns output element o.
__global__ void k_layer(const float* __restrict__ xin, const int* __restrict__ offs,
                        const int* __restrict__ csr, const float* __restrict__ deg,
                        const float* __restrict__ Wt_l, const float* __restrict__ root_w_l,
                        const float* __restrict__ conv_b_l, float* __restrict__ xout,
                        int do_relu) {
    int tid = blockIdx.x * 256 + threadIdx.x;
    int n = tid >> 5, o = tid & 31;
    int base = threadIdx.x & 32;           // which half of the wave64
    int e0 = offs[n];
    float dg = deg[n];
    int e1 = e0 + (int)dg;
    float acc = 0.f;
    for (int e = e0; e < e1; ++e) {
        int packed = csr[e];               // all 32 lanes same address -> broadcast
        int s = packed & 16383;
        int t = packed >> 14;
        float xv = xin[s * H + o];         // coalesced 128B per half-wave
        const float* __restrict__ W = Wt_l + t * 1024;
#pragma unroll
        for (int i = 0; i < H; ++i)
            acc += __shfl(xv, base + i) * W[i * H + o];
    }
    acc /= (dg < 1.f ? 1.f : dg);
    float xs = xin[tid];
    float accR = conv_b_l[o];
#pragma unroll
    for (int i = 0; i < H; ++i)
        accR += __shfl(xs, base + i) * root_w_l[i * H + o];
    float v = acc + accR;
    if (do_relu) v = v > 0.f ? v : 0.f;
    xout[tid] = v;
}

// ---- readout: one thread per output element (B x 128) ----
__global__ void k_final(const float* __restrict__ x, const int* __restrict__ metal_idx,
                        const int* __restrict__ loop_edge, const int* __restrict__ loop_pair,
                        const float* __restrict__ f_w, const float* __restrict__ f_b,
                        float* __restrict__ out) {
    int tid = blockIdx.x * blockDim.x + threadIdx.x;
    if (tid >= BB * 128) return;
    int b = tid >> 7, j = tid & 127;
    int mg = metal_idx[b] + b * NPER;
    const float* __restrict__ xm = x + mg * H;
    int p0, p1;
    if (j < 64) {
        p0 = loop_edge[(b * 64 + j) * 2];
        p1 = loop_edge[(b * 64 + j) * 2 + 1];
    } else {
        int j2 = j - 64;
        p0 = loop_pair[(b * 64 + j2) * 2];
        p1 = loop_pair[(b * 64 + j2) * 2 + 1];
    }
    const float* __restrict__ xs = x + (b * NPER + p0) * H;
    const float* __restrict__ xt = x + (b * NPER + p1) * H;
    float fh = f_b[0];
    float pp = 0.f;
#pragma unroll
    for (int h = 0; h < H; ++h) {
        float m = xm[h];
        fh += m * f_w[h];
        pp += m * (xs[h] + xt[h]) - xs[h] * xt[h];
    }
    out[tid] = (j < 64) ? (pp - fh) : (-pp);
}

extern "C" void kernel_launch(void* const* d_in, const int* in_sizes, int n_in,
                              void* d_out, int out_size, void* d_ws, size_t ws_size,
                              hipStream_t stream) {
    const int*   x_nodes    = (const int*)d_in[0];
    const int*   edge_index = (const int*)d_in[1];
    const int*   src        = edge_index;
    const int*   dst        = edge_index + NE;
    const int*   edge_attr  = (const int*)d_in[2];
    const int*   metal_idx  = (const int*)d_in[3];
    const int*   loop_edge  = (const int*)d_in[4];
    const int*   loop_pair  = (const int*)d_in[5];
    const float* node_emb   = (const float*)d_in[6];
    const float* edge_emb   = (const float*)d_in[7];
    const float* lin_w      = (const float*)d_in[8];
    const float* lin_b      = (const float*)d_in[9];
    const float* root_w     = (const float*)d_in[10];
    const float* conv_b     = (const float*)d_in[11];
    const float* f_w        = (const float*)d_in[12];
    const float* f_b        = (const float*)d_in[13];
    float* out = (float*)d_out;

    float* ws   = (float*)d_ws;
    float* xA   = ws;                         // NN*H
    float* xB   = xA + NN * H;                // NN*H
    float* deg  = xB + NN * H;                // NN   (zeroed)
    int*   cnt  = (int*)(deg + NN);           // NN   (zeroed, contiguous with deg)
    int*   offs = cnt + NN;                   // NN
    int*   csr  = offs + NN;                  // NE
    float* Wt   = (float*)(csr + NE);         // NL*16*1024

    // zero deg + cnt in one fill (contiguous 128KB)
    hipMemsetAsync(deg, 0, 2 * NN * sizeof(float), stream);

    k_prep<<<BLK_DEG + BLK_EMB + BLK_W, 256, 0, stream>>>(
        dst, x_nodes, node_emb, edge_emb, lin_w, lin_b, deg, xA, Wt);
    k_scan<<<1, 1024, 0, stream>>>(deg, offs);
    k_scatter<<<NE / 256, 256, 0, stream>>>(src, dst, edge_attr, offs, cnt, csr);

    float* xin = xA;
    float* xout = xB;
    for (int l = 0; l < NL; ++l) {
        k_layer<<<NN * H / 256, 256, 0, stream>>>(
            xin, offs, csr, deg, Wt + l * 16 * 1024, root_w + l * H * H, conv_b + l * H,
            xout, l < NL - 1 ? 1 : 0);
        float* tmp = xin; xin = xout; xout = tmp;
    }

    k_final<<<(BB * 128 + 255) / 256, 256, 0, stream>>>(
        xin, metal_idx, loop_edge, loop_pair, f_w, f_b, out);
}

// Round 3
// 90.657 us; speedup vs baseline: 3.0607x; 3.0607x over previous
//
#include <hip/hip_runtime.h>

#define NN 16384      // nodes
#define NE 65536      // edges
#define H  32
#define BB 32
#define NPERB 512

// ---- fused prep:
//  tasks [0, 512K)        : x0 = node_emb[x_nodes]            (n*32+h)
//  tasks [512K, 576K)     : Wt[l][t][i][o] per-type matrices  (all 4 layers)
//  tasks [576K, 640K)     : packed edge = src|dst<<14|ty<<28  + deg histogram
//  tasks [640K, 1152K)    : zero buf1 (first layer's accumulator)
__global__ void k_prep(const int* __restrict__ x_nodes, const int* __restrict__ edge_index,
                       const int* __restrict__ edge_attr,
                       const float* __restrict__ node_emb, const float* __restrict__ edge_emb,
                       const float* __restrict__ lin_w, const float* __restrict__ lin_b,
                       float* __restrict__ x0, float* __restrict__ Wt,
                       unsigned int* __restrict__ packed, float* __restrict__ degf,
                       float* __restrict__ zbuf) {
    int t = blockIdx.x * 256 + threadIdx.x;
    if (t < 524288) {
        int n = t >> 5, h = t & 31;
        x0[t] = node_emb[x_nodes[n] * H + h];
    } else if (t < 589824) {
        int w = t - 524288;               // l*16384 + ty*1024 + io
        int l = w >> 14, rest = w & 16383;
        int ty = rest >> 10, io = rest & 1023;
        float acc = lin_b[l * 1024 + io];
#pragma unroll
        for (int j = 0; j < 8; ++j) {
            float e = edge_emb[(l * 16 + ty) * 8 + j];
            e = e > 0.f ? e : 0.f;
            acc = fmaf(e, lin_w[(l * 8 + j) * 1024 + io], acc);
        }
        Wt[w] = acc;
    } else if (t < 655360) {
        int e = t - 589824;
        unsigned int s  = (unsigned int)edge_index[e];
        unsigned int d  = (unsigned int)edge_index[NE + e];
        unsigned int ty = (unsigned int)edge_attr[e];
        packed[e] = s | (d << 14) | (ty << 28);
        atomicAdd(&degf[d], 1.0f);
    } else {
        zbuf[t - 655360] = 0.f;           // 512K zero tasks
    }
}

// ---- one fused layer: edge scatter (pre-scaled by 1/deg) + self root-term + zero next buffer.
// Input is PRE-activation of previous layer; relu applied on the fly (relu_in).
//  tasks [0, 2M)        : edge task, 32 lanes/edge, lane o owns output elem o
//  tasks [2M, 2.5M)     : self task: out[n] += x[n]@root + b
//  tasks [2.5M, 3M)     : zero the third buffer for layer l+1
__global__ void k_phase(const float* __restrict__ xin, float* __restrict__ xout,
                        float* __restrict__ zbuf,
                        const unsigned int* __restrict__ packed, const float* __restrict__ degf,
                        const float* __restrict__ Wt_l, const float* __restrict__ root_l,
                        const float* __restrict__ b_l, int relu_in) {
    int t = blockIdx.x * 256 + threadIdx.x;
    int base = threadIdx.x & 32;          // half-wave base for shfl broadcast
    if (t < 2097152) {
        int e = t >> 5, o = t & 31;
        unsigned int p = packed[e];       // broadcast across the 32-lane group
        int s  = p & 16383;
        int d  = (p >> 14) & 16383;
        int ty = p >> 28;
        float xv = xin[s * H + o];        // coalesced 128B per half-wave
        if (relu_in) xv = xv > 0.f ? xv : 0.f;
        float invd = __builtin_amdgcn_rcpf(fmaxf(degf[d], 1.0f));
        const float* __restrict__ W = Wt_l + ty * 1024 + o;
        float acc = 0.f;
#pragma unroll
        for (int i = 0; i < 32; ++i)
            acc = fmaf(__shfl(xv, base + i), W[i * 32], acc);
        atomicAdd(&xout[d * H + o], acc * invd);
    } else if (t < 2621440) {
        int t2 = t - 2097152;
        int o = t2 & 31;
        float xv = xin[t2];
        if (relu_in) xv = xv > 0.f ? xv : 0.f;
        float acc = b_l[o];
#pragma unroll
        for (int i = 0; i < 32; ++i)
            acc = fmaf(__shfl(xv, base + i), root_l[i * 32 + o], acc);
        atomicAdd(&xout[t2], acc);
    } else if (zbuf) {
        zbuf[t - 2621440] = 0.f;
    }
}

// ---- readout: one thread per output element (B x 128); input is p4 (no relu on last layer)
__global__ void k_final(const float* __restrict__ x, const int* __restrict__ metal_idx,
                        const int* __restrict__ loop_edge, const int* __restrict__ loop_pair,
                        const float* __restrict__ f_w, const float* __restrict__ f_b,
                        float* __restrict__ out) {
    int tid = blockIdx.x * blockDim.x + threadIdx.x;
    if (tid >= BB * 128) return;
    int b = tid >> 7, j = tid & 127;
    int mg = metal_idx[b] + b * NPERB;
    const float* __restrict__ xm = x + mg * H;
    int p0, p1;
    if (j < 64) {
        p0 = loop_edge[(b * 64 + j) * 2];
        p1 = loop_edge[(b * 64 + j) * 2 + 1];
    } else {
        int j2 = j - 64;
        p0 = loop_pair[(b * 64 + j2) * 2];
        p1 = loop_pair[(b * 64 + j2) * 2 + 1];
    }
    const float* __restrict__ xs = x + (b * NPERB + p0) * H;
    const float* __restrict__ xt = x + (b * NPERB + p1) * H;
    float fh = f_b[0];
    float pp = 0.f;
#pragma unroll
    for (int h = 0; h < H; ++h) {
        float m = xm[h];
        fh = fmaf(m, f_w[h], fh);
        pp += m * (xs[h] + xt[h]) - xs[h] * xt[h];
    }
    out[tid] = (j < 64) ? (pp - fh) : (-pp);
}

extern "C" void kernel_launch(void* const* d_in, const int* in_sizes, int n_in,
                              void* d_out, int out_size, void* d_ws, size_t ws_size,
                              hipStream_t stream) {
    const int*   x_nodes    = (const int*)d_in[0];
    const int*   edge_index = (const int*)d_in[1];
    const int*   edge_attr  = (const int*)d_in[2];
    const int*   metal_idx  = (const int*)d_in[3];
    const int*   loop_edge  = (const int*)d_in[4];
    const int*   loop_pair  = (const int*)d_in[5];
    const float* node_emb   = (const float*)d_in[6];
    const float* edge_emb   = (const float*)d_in[7];
    const float* lin_w      = (const float*)d_in[8];
    const float* lin_b      = (const float*)d_in[9];
    const float* root_w     = (const float*)d_in[10];
    const float* conv_b     = (const float*)d_in[11];
    const float* f_w        = (const float*)d_in[12];
    const float* f_b        = (const float*)d_in[13];
    float* out = (float*)d_out;

    float* ws   = (float*)d_ws;
    float* buf0 = ws;                          // NN*H
    float* buf1 = buf0 + NN * H;               // NN*H
    float* buf2 = buf1 + NN * H;               // NN*H
    float* degf = buf2 + NN * H;               // NN (memset to 0)
    unsigned int* packed = (unsigned int*)(degf + NN);   // NE
    float* Wt   = (float*)(packed + NE);       // 4*16*1024

    hipMemsetAsync(degf, 0, NN * sizeof(float), stream);

    k_prep<<<4608, 256, 0, stream>>>(x_nodes, edge_index, edge_attr, node_emb, edge_emb,
                                     lin_w, lin_b, buf0, Wt, packed, degf, buf1);

    // layer l: in -> out (pre-zeroed), zero the third buffer for layer l+1
    // l=0: buf0 -> buf1, zero buf2      (relu_in = 0, x0 is raw embedding)
    // l=1: buf1 -> buf2, zero buf0      (relu_in = 1)
    // l=2: buf2 -> buf0, zero buf1
    // l=3: buf0 -> buf1, no zero
    k_phase<<<12288, 256, 0, stream>>>(buf0, buf1, buf2, packed, degf,
                                       Wt + 0 * 16384, root_w + 0 * 1024, conv_b + 0 * H, 0);
    k_phase<<<12288, 256, 0, stream>>>(buf1, buf2, buf0, packed, degf,
                                       Wt + 1 * 16384, root_w + 1 * 1024, conv_b + 1 * H, 1);
    k_phase<<<12288, 256, 0, stream>>>(buf2, buf0, buf1, packed, degf,
                                       Wt + 2 * 16384, root_w + 2 * 1024, conv_b + 2 * H, 1);
    k_phase<<<10240, 256, 0, stream>>>(buf0, buf1, (float*)0, packed, degf,
                                       Wt + 3 * 16384, root_w + 3 * 1024, conv_b + 3 * H, 1);

    k_final<<<16, 256, 0, stream>>>(buf1, metal_idx, loop_edge, loop_pair, f_w, f_b, out);
}